// Round 2
// baseline (2332.075 us; speedup 1.0000x reference)
//
#include <hip/hip_runtime.h>
#include <hip/hip_fp16.h>
#include <hip/hip_cooperative_groups.h>

namespace cg = cooperative_groups;

#define TEMP_ 0.2
#define NITER 10

typedef _Float16 half_t;
struct __align__(8)  H4 { half_t h[4]; };
struct __align__(16) H8 { half_t h[8]; };

__device__ __forceinline__ float wsum(float v){
#pragma unroll
  for (int o = 32; o > 0; o >>= 1) v += __shfl_down(v, o, 64);
  return v;
}
__device__ __forceinline__ double wsumd(double v){
#pragma unroll
  for (int o = 32; o > 0; o >>= 1) v += __shfl_down(v, o, 64);
  return v;
}
__device__ __forceinline__ float wmin(float v){
#pragma unroll
  for (int o = 32; o > 0; o >>= 1) v = fminf(v, __shfl_down(v, o, 64));
  return v;
}

// order-preserving float<->uint map
__device__ __forceinline__ unsigned fenc(float f){
  unsigned u = __float_as_uint(f);
  return (u & 0x80000000u) ? ~u : (u | 0x80000000u);
}
__device__ __forceinline__ float fdec(unsigned u){
  return (u & 0x80000000u) ? __uint_as_float(u & 0x7FFFFFFFu) : __uint_as_float(~u);
}

__global__ __launch_bounds__(256, 4) void sink_all(
    const float* __restrict__ cd, const float* __restrict__ A, const float* __restrict__ B,
    float* __restrict__ T, half_t* __restrict__ E,
    double* __restrict__ sums, double* __restrict__ Ssum, unsigned* __restrict__ minbits,
    float* __restrict__ csA, float* __restrict__ csB, float* __restrict__ rowsum,
    int N, int M)
{
  cg::grid_group grid = cg::this_grid();
  const int tid  = threadIdx.x;
  const int lane = tid & 63, wid = tid >> 6;
  const long long gtid     = (long long)blockIdx.x * 256 + tid;
  const long long nthreads = (long long)gridDim.x * 256;

  __shared__ double sd[8];
  __shared__ float  sf[64];

  // ---- phase 0: zero accumulators ----
  for (long long i = gtid; i < M; i += nthreads){ csA[i] = 0.f; csB[i] = 0.f; }
  if (gtid == 0){ sums[0] = 0.0; sums[1] = 0.0; *Ssum = 0.0; *minbits = 0xFFFFFFFFu; }
  grid.sync();

  // ---- phase 1: min / sum / sumsq over cdist ----
  {
    const float4* c4 = (const float4*)cd;
    long long n4 = (long long)N * M / 4;
    double s = 0.0, ss = 0.0;
    float fs = 0.f, fss = 0.f;
    float mn = __int_as_float(0x7F800000);
    int cnt = 0;
    for (long long i = gtid; i < n4; i += nthreads){
      float4 v = c4[i];
      mn = fminf(mn, fminf(fminf(v.x, v.y), fminf(v.z, v.w)));
      fs  += (v.x + v.y) + (v.z + v.w);
      fss += v.x*v.x + v.y*v.y + v.z*v.z + v.w*v.w;
      if (++cnt == 8){ s += fs; ss += fss; fs = 0.f; fss = 0.f; cnt = 0; }
    }
    s += fs; ss += fss;
    s = wsumd(s); ss = wsumd(ss); mn = wmin(mn);
    if (lane == 0){ sd[wid] = s; sd[4 + wid] = ss; sf[wid] = mn; }
    __syncthreads();
    if (tid == 0){
      unsafeAtomicAdd(&sums[0], sd[0] + sd[1] + sd[2] + sd[3]);
      unsafeAtomicAdd(&sums[1], sd[4] + sd[5] + sd[6] + sd[7]);
      atomicMin(minbits, fenc(fminf(fminf(sf[0], sf[1]), fminf(sf[2], sf[3]))));
    }
    __syncthreads();
  }
  grid.sync();

  // ---- stats (every thread) ----
  float cmin, kscale;
  {
    long long NM = (long long)N * M;
    double s = sums[0], ss = sums[1];
    double mean = s / (double)NM;
    double var  = (ss - mean * s) / (double)(NM - 1);   // ddof=1
    cmin  = fdec(*minbits);
    kscale = (float)(1.0 / (sqrt(var) * TEMP_));
  }

  const int TBX = M / 1024;
  const int TB  = TBX * (N / 64);
  const int NG  = N / 8;

  // ---- phase 2: E = exp fp16, colsum (u=1) -> csA, total S ----
  for (int t = blockIdx.x; t < TB; t += gridDim.x){
    int bx = t % TBX, by = t / TBX;
    int c0 = bx * 1024 + tid * 4;
    int r0 = by * 64;
    float a0 = 0.f, a1 = 0.f, a2 = 0.f, a3 = 0.f;
#pragma unroll 4
    for (int r = 0; r < 64; ++r){
      long long idx = (long long)(r0 + r) * M + c0;
      float4 v = *(const float4*)(cd + idx);
      float e0 = __expf((cmin - v.x) * kscale);
      float e1 = __expf((cmin - v.y) * kscale);
      float e2 = __expf((cmin - v.z) * kscale);
      float e3 = __expf((cmin - v.w) * kscale);
      H4 o; o.h[0] = (half_t)e0; o.h[1] = (half_t)e1; o.h[2] = (half_t)e2; o.h[3] = (half_t)e3;
      *(H4*)(E + idx) = o;
      a0 += e0; a1 += e1; a2 += e2; a3 += e3;
    }
    unsafeAtomicAdd(&csA[c0 + 0], a0);
    unsafeAtomicAdd(&csA[c0 + 1], a1);
    unsafeAtomicAdd(&csA[c0 + 2], a2);
    unsafeAtomicAdd(&csA[c0 + 3], a3);
    float tot = wsum((a0 + a1) + (a2 + a3));
    __syncthreads();                 // protect sf reuse across t iterations
    if (lane == 0) sf[wid] = tot;
    __syncthreads();
    if (tid == 0) unsafeAtomicAdd(Ssum, (double)(sf[0] + sf[1] + sf[2] + sf[3]));
  }
  grid.sync();

  const float Sf = (float)(*Ssum);

  // ---- Sinkhorn loop: 10 row passes, 9 col passes (col#0 fused in phase 2) ----
  float* cur = csA;   // colsum feeding v this iteration
  float* nxt = csB;   // colsum accumulated by this iteration's col pass
  for (int it = 0; it < NITER; ++it){
    // zero nxt (dead buffer; col-phase atomics start only after next grid.sync)
    for (long long i = gtid; i < M; i += nthreads) nxt[i] = 0.f;

    // row phase: rowsum_i = sum_j E_ij * v_j,  v_j = B_j*S/cur_j  (on the fly)
    for (int g = blockIdx.x; g < NG; g += gridDim.x){
      int r0 = g * 8;
      float vr[32];
#pragma unroll
      for (int k = 0; k < 4; ++k){
        int c = k * 2048 + tid * 8;
        float4 a  = *(const float4*)(cur + c);
        float4 b  = *(const float4*)(cur + c + 4);
        float4 ba = *(const float4*)(B + c);
        float4 bb = *(const float4*)(B + c + 4);
        vr[k*8+0] = ba.x * Sf / a.x; vr[k*8+1] = ba.y * Sf / a.y;
        vr[k*8+2] = ba.z * Sf / a.z; vr[k*8+3] = ba.w * Sf / a.w;
        vr[k*8+4] = bb.x * Sf / b.x; vr[k*8+5] = bb.y * Sf / b.y;
        vr[k*8+6] = bb.z * Sf / b.z; vr[k*8+7] = bb.w * Sf / b.w;
      }
      for (int r = 0; r < 8; ++r){
        const half_t* Er = E + (long long)(r0 + r) * M;
        float p = 0.f;
#pragma unroll
        for (int k = 0; k < 4; ++k){
          H8 hh = *(const H8*)(Er + k * 2048 + tid * 8);
          p += (float)hh.h[0]*vr[k*8+0] + (float)hh.h[1]*vr[k*8+1]
             + (float)hh.h[2]*vr[k*8+2] + (float)hh.h[3]*vr[k*8+3]
             + (float)hh.h[4]*vr[k*8+4] + (float)hh.h[5]*vr[k*8+5]
             + (float)hh.h[6]*vr[k*8+6] + (float)hh.h[7]*vr[k*8+7];
        }
        p = wsum(p);
        if (lane == 0) sf[wid * 8 + r] = p;
      }
      __syncthreads();
      if (tid < 8) rowsum[r0 + tid] = sf[tid] + sf[8 + tid] + sf[16 + tid] + sf[24 + tid];
      __syncthreads();
    }
    grid.sync();

    if (it == NITER - 1) break;

    // col phase: nxt_j += sum_i u_i E_ij,  u_i = A_i*S/rowsum_i  (on the fly)
    for (int t = blockIdx.x; t < TB; t += gridDim.x){
      int bx = t % TBX, by = t / TBX;
      int r0 = by * 64;
      __syncthreads();
      if (tid < 64) sf[tid] = A[r0 + tid] * Sf / rowsum[r0 + tid];
      __syncthreads();
      int c0 = bx * 1024 + tid * 4;
      float a0 = 0.f, a1 = 0.f, a2 = 0.f, a3 = 0.f;
#pragma unroll 4
      for (int r = 0; r < 64; ++r){
        float ur = sf[r];
        H4 hh = *(const H4*)(E + (long long)(r0 + r) * M + c0);
        a0 += ur * (float)hh.h[0];
        a1 += ur * (float)hh.h[1];
        a2 += ur * (float)hh.h[2];
        a3 += ur * (float)hh.h[3];
      }
      unsafeAtomicAdd(&nxt[c0 + 0], a0);
      unsafeAtomicAdd(&nxt[c0 + 1], a1);
      unsafeAtomicAdd(&nxt[c0 + 2], a2);
      unsafeAtomicAdd(&nxt[c0 + 3], a3);
    }
    grid.sync();
    float* tmp = cur; cur = nxt; nxt = tmp;
  }

  // ---- final: T_ij = (A_i/rowsum_i) * (B_j*S/cur_j) * E_ij ----
  for (int g = blockIdx.x; g < NG; g += gridDim.x){
    int r0 = g * 8;
    float vr[32];
#pragma unroll
    for (int k = 0; k < 4; ++k){
      int c = k * 2048 + tid * 8;
      float4 a  = *(const float4*)(cur + c);
      float4 b  = *(const float4*)(cur + c + 4);
      float4 ba = *(const float4*)(B + c);
      float4 bb = *(const float4*)(B + c + 4);
      vr[k*8+0] = ba.x * Sf / a.x; vr[k*8+1] = ba.y * Sf / a.y;
      vr[k*8+2] = ba.z * Sf / a.z; vr[k*8+3] = ba.w * Sf / a.w;
      vr[k*8+4] = bb.x * Sf / b.x; vr[k*8+5] = bb.y * Sf / b.y;
      vr[k*8+6] = bb.z * Sf / b.z; vr[k*8+7] = bb.w * Sf / b.w;
    }
    for (int r = 0; r < 8; ++r){
      int row = r0 + r;
      float uf = A[row] / rowsum[row];
#pragma unroll
      for (int k = 0; k < 4; ++k){
        long long idx = (long long)row * M + k * 2048 + tid * 8;
        H8 hh = *(const H8*)(E + idx);
        float4 oa, ob;
        oa.x = uf * vr[k*8+0] * (float)hh.h[0];
        oa.y = uf * vr[k*8+1] * (float)hh.h[1];
        oa.z = uf * vr[k*8+2] * (float)hh.h[2];
        oa.w = uf * vr[k*8+3] * (float)hh.h[3];
        ob.x = uf * vr[k*8+4] * (float)hh.h[4];
        ob.y = uf * vr[k*8+5] * (float)hh.h[5];
        ob.z = uf * vr[k*8+6] * (float)hh.h[6];
        ob.w = uf * vr[k*8+7] * (float)hh.h[7];
        *(float4*)(T + idx)     = oa;
        *(float4*)(T + idx + 4) = ob;
      }
    }
  }
}

extern "C" void kernel_launch(void* const* d_in, const int* in_sizes, int n_in,
                              void* d_out, int out_size, void* d_ws, size_t ws_size,
                              hipStream_t stream){
  const float* cd = (const float*)d_in[0];
  const float* A  = (const float*)d_in[1];
  const float* B  = (const float*)d_in[2];
  int N = in_sizes[1];
  int M = in_sizes[2];
  float* T = (float*)d_out;

  // ws layout: scalars | csA | csB | rowsum | (1 MB align) | E fp16
  char* ws = (char*)d_ws;
  double*   sums    = (double*)ws;
  double*   Ssum    = (double*)(ws + 16);
  unsigned* minbits = (unsigned*)(ws + 24);
  float*    csA     = (float*)(ws + 64);
  float*    csB     = csA + M;
  float*    rowsum  = csB + M;
  half_t*   E       = (half_t*)(ws + (1 << 20));

  int occ = 4;
  if (hipOccupancyMaxActiveBlocksPerMultiprocessor(&occ, sink_all, 256, 0) != hipSuccess || occ < 1)
    occ = 4;
  int G = occ * 256;            // 256 CUs on MI355X
  int maxG = N / 8;             // natural work granularity ceiling
  if (G > maxG) G = maxG;

  void* args[] = { (void*)&cd, (void*)&A, (void*)&B, (void*)&T, (void*)&E,
                   (void*)&sums, (void*)&Ssum, (void*)&minbits,
                   (void*)&csA, (void*)&csB, (void*)&rowsum,
                   (void*)&N, (void*)&M };
  hipLaunchCooperativeKernel((const void*)sink_all, dim3(G), dim3(256), args, 0, stream);
}